// Round 11
// baseline (46.143 us; speedup 1.0000x reference)
//
#include <hip/hip_runtime.h>
#include <hip/hip_bf16.h>
#include <math.h>

constexpr int Bn = 1024;   // batch
constexpr int Cn = 1000;   // classes
constexpr int Dn = 256;    // feature dim
constexpr float EPS = 1e-4f;
constexpr unsigned SENTINEL = 0x5A17C0DEu;

typedef __attribute__((ext_vector_type(8))) short bf16x8;
typedef __attribute__((ext_vector_type(4))) float f32x4;

static __device__ __forceinline__ unsigned short f2bf(float x) {
    union { float f; unsigned u; } v; v.f = x;
    return (unsigned short)((v.u + 0x7fffu + ((v.u >> 16) & 1u)) >> 16);
}
static __device__ __forceinline__ float bf2f(unsigned short h) {
    union { unsigned u; float f; } v; v.u = ((unsigned)h) << 16; return v.f;
}
static __device__ __forceinline__ bf16x8 cvt8(const float4 lo, const float4 hi) {
    bf16x8 r;
    r[0] = (short)f2bf(lo.x); r[1] = (short)f2bf(lo.y);
    r[2] = (short)f2bf(lo.z); r[3] = (short)f2bf(lo.w);
    r[4] = (short)f2bf(hi.x); r[5] = (short)f2bf(hi.y);
    r[6] = (short)f2bf(hi.z); r[7] = (short)f2bf(hi.w);
    return r;
}

// ---------------------------------------------------------------------------
// Single launch, 512 blocks x 256 threads (4 waves), 2 blocks/CU co-resident.
//
// PRODUCE  (tile = bid: rg = bid>>2 in [0,128), cq = bid&3):
//   W rows [rg*16, rg*16+16) x cols [cq*64, +64) of Wb = bf16(G@F),
//   G = [z ; mu_clamped] (2048 rows). Also rn_part[row][ci] (16-col norm
//   partials of rounded Wb) and epsn[row] (eps*||G_row||^2, bf16-rounded).
//   Then __threadfence() + release-store flags[bid] = SENTINEL.
//
// CONSUME  (tile: r = bid>>4 in [0,32), c = bid&15):
//   spin-acquire the 24 producer flags covering W rows [r*32,+32) and
//   [1024+c*64,+64), then out[32x64] = Y.U^T + rowbias + colbias
//   (identical to R10's out_kernel body).
//
// Correctness is timing-independent: W/rn/epsn values are replay-invariant,
// so any stale-cache read across replays is same-value; first post-poison
// replay waits properly (0xAAAAAAAA != SENTINEL).
__global__ __launch_bounds__(256, 2) void lda_pipe(const float* __restrict__ z,
                                                   const float* __restrict__ mu,
                                                   const float* __restrict__ logits,
                                                   const float* __restrict__ F,
                                                   unsigned short* __restrict__ Wb,   // [2048][256]
                                                   float* __restrict__ rn_part,       // [2048][16]
                                                   float* __restrict__ epsn,          // [2048]
                                                   unsigned* __restrict__ flags,      // [512]
                                                   float* __restrict__ out) {         // [1024][1000]
    __shared__ float rowbias[32], colbias[64];
    const int bid = blockIdx.x, tid = threadIdx.x;
    const int lane = tid & 63, w = tid >> 6;
    const int la = lane & 15, kg = lane >> 4;

    // ================= PRODUCE =================
    {
        const int rg = bid >> 2, cq = bid & 3;
        const int grow = rg * 16 + la;
        const float* ap = (grow < 1024) ? &z[(size_t)grow * Dn]
                                        : &mu[(size_t)min(grow - 1024, Cn - 1) * Dn];
        bf16x8 af[8];
        float zs = 0.f;
#pragma unroll
        for (int kt = 0; kt < 8; ++kt) {
            const int k0 = kt * 32 + kg * 8;
            af[kt] = cvt8(*(const float4*)&ap[k0], *(const float4*)&ap[k0 + 4]);
#pragma unroll
            for (int j = 0; j < 8; ++j) {
                const float v = bf2f((unsigned short)af[kt][j]);
                zs = fmaf(v, v, zs);
            }
        }
        const int bcol = cq * 64 + w * 16 + la;
        f32x4 acc = {0.f, 0.f, 0.f, 0.f};
#pragma unroll
        for (int kt = 0; kt < 8; ++kt) {
            const int k0 = kt * 32 + kg * 8;
            bf16x8 bf;
#pragma unroll
            for (int j = 0; j < 8; ++j) bf[j] = (short)f2bf(F[(size_t)(k0 + j) * Dn + bcol]);
            acc = __builtin_amdgcn_mfma_f32_16x16x32_bf16(af[kt], bf, acc, 0, 0, 0);
        }
        // C/D: col = la, row = kg*4 + j
        float np[4];
#pragma unroll
        for (int j = 0; j < 4; ++j) {
            const unsigned short h = f2bf(acc[j]);
            Wb[(size_t)(rg * 16 + kg * 4 + j) * Dn + bcol] = h;
            const float v = bf2f(h);
            float s = v * v;
            s += __shfl_xor(s, 1); s += __shfl_xor(s, 2);
            s += __shfl_xor(s, 4); s += __shfl_xor(s, 8);
            np[j] = s;
        }
        if (la == 0) {
#pragma unroll
            for (int j = 0; j < 4; ++j)
                rn_part[(size_t)(rg * 16 + kg * 4 + j) * 16 + cq * 4 + w] = np[j];
        }
        zs += __shfl_xor(zs, 16);
        zs += __shfl_xor(zs, 32);
        if (cq == 0 && w == 0 && kg == 0) epsn[rg * 16 + la] = EPS * zs;

        __syncthreads();   // all of this block's W/rn/epsn stores issued
        if (tid == 0) {
            __threadfence();   // device-scope visibility for the block's writes
            __hip_atomic_store(&flags[bid], SENTINEL, __ATOMIC_RELEASE,
                               __HIP_MEMORY_SCOPE_AGENT);
        }
    }

    // ================= CONSUME =================
    const int r = bid >> 4;    // 0..31  (32 z-row tiles of 32)
    const int c = bid & 15;    // 0..15  (16 class tiles of 64)

    // per-wave LSE (waves 0,1 only — the bias-building threads)
    float lse = 0.f;
    if (w < 2) {
        float mx = -INFINITY;
        for (int i = lane; i < Cn; i += 64) mx = fmaxf(mx, logits[i]);
#pragma unroll
        for (int off = 32; off > 0; off >>= 1) mx = fmaxf(mx, __shfl_xor(mx, off));
        float sm = 0.f;
        for (int i = lane; i < Cn; i += 64) sm += expf(logits[i] - mx);
#pragma unroll
        for (int off = 32; off > 0; off >>= 1) sm += __shfl_xor(sm, off);
        lse = mx + logf(sm);
    }

    // wait for the 24 producer tiles this block consumes
    if (tid < 24) {
        const int fi = (tid < 8) ? (8 * r + tid)                  // z rows: rg=2r+e, cq
                                 : (256 + 16 * c + (tid - 8));    // mu rows: rg=64+4c+d, cq
        while (__hip_atomic_load(&flags[fi], __ATOMIC_ACQUIRE,
                                 __HIP_MEMORY_SCOPE_AGENT) != SENTINEL) {}
    }
    __syncthreads();

    // biases
    if (tid < 32) {
        const int rr = r * 32 + tid;
        const float4* p = (const float4*)&rn_part[(size_t)rr * 16];
        const float4 a = p[0], b = p[1], cc = p[2], d = p[3];
        const float s = a.x + a.y + a.z + a.w + b.x + b.y + b.z + b.w +
                        cc.x + cc.y + cc.z + cc.w + d.x + d.y + d.z + d.w;
        rowbias[tid] = -0.5f * (s + epsn[rr]);
    } else if (tid < 96) {
        const int lc = tid - 32, gc = c * 64 + lc;
        float v = 0.f;
        if (gc < Cn) {
            const int rr = 1024 + gc;
            const float4* p = (const float4*)&rn_part[(size_t)rr * 16];
            const float4 a = p[0], b = p[1], cc = p[2], d = p[3];
            const float s = a.x + a.y + a.z + a.w + b.x + b.y + b.z + b.w +
                            cc.x + cc.y + cc.z + cc.w + d.x + d.y + d.z + d.w;
            v = logits[gc] - lse - 0.5f * (s + epsn[rr]);
        }
        colbias[lc] = v;
    }
    __syncthreads();

    // 32x64 output tile: wave = 16x32 (2 MFMA chains), frags from global Wb
    const int wr = (w >> 1) * 16, wc = (w & 1) * 32;
    const bf16x8* pa  = (const bf16x8*)&Wb[(size_t)(r * 32 + wr + la) * Dn + kg * 8];
    const bf16x8* pb0 = (const bf16x8*)&Wb[(size_t)(1024 + c * 64 + wc + la) * Dn + kg * 8];
    const bf16x8* pb1 = pb0 + 512;   // +16 rows

    f32x4 c0 = {0.f, 0.f, 0.f, 0.f}, c1 = {0.f, 0.f, 0.f, 0.f};
#pragma unroll
    for (int kt = 0; kt < 8; ++kt) {
        const bf16x8 a  = pa[kt * 4];
        const bf16x8 b0 = pb0[kt * 4];
        const bf16x8 b1 = pb1[kt * 4];
        c0 = __builtin_amdgcn_mfma_f32_16x16x32_bf16(a, b0, c0, 0, 0, 0);
        c1 = __builtin_amdgcn_mfma_f32_16x16x32_bf16(a, b1, c1, 0, 0, 0);
    }

    // C/D: col = la, row = kg*4 + j
#pragma unroll
    for (int j = 0; j < 4; ++j) {
        const int rl = wr + kg * 4 + j;
        const int gr = r * 32 + rl;
        const float rb = rowbias[rl];
        const int gc0 = c * 64 + wc + la;
        const int gc1 = gc0 + 16;
        if (gc0 < Cn) out[(size_t)gr * Cn + gc0] = c0[j] + rb + colbias[wc + la];
        if (gc1 < Cn) out[(size_t)gr * Cn + gc1] = c1[j] + rb + colbias[wc + 16 + la];
    }
}

// ---------------------------------------------------------------------------
extern "C" void kernel_launch(void* const* d_in, const int* in_sizes, int n_in,
                              void* d_out, int out_size, void* d_ws, size_t ws_size,
                              hipStream_t stream) {
    const float* z      = (const float*)d_in[0];   // [1024][256]
    const float* mu     = (const float*)d_in[1];   // [1000][256]
    const float* logits = (const float*)d_in[2];   // [1000]
    const float* F      = (const float*)d_in[3];   // [256][256]
    float* out = (float*)d_out;                    // [1024][1000]

    char* ws = (char*)d_ws;
    unsigned short* Wb = (unsigned short*)(ws);                 // 1 MB   [2048][256]
    float* rn_part = (float*)(ws + (1 << 20));                  // 128 KB [2048][16]
    float* epsn    = (float*)(ws + (1 << 20) + (128 << 10));    // 8 KB   [2048]
    unsigned* flags = (unsigned*)(ws + (1 << 20) + (136 << 10)); // 2 KB  [512]

    lda_pipe<<<dim3(512), dim3(256), 0, stream>>>(z, mu, logits, F,
                                                  Wb, rn_part, epsn, flags, out);
}

// Round 12
// 21.474 us; speedup vs baseline: 2.1488x; 2.1488x over previous
//
#include <hip/hip_runtime.h>
#include <hip/hip_bf16.h>
#include <math.h>

constexpr int Bn = 1024;   // batch
constexpr int Cn = 1000;   // classes
constexpr int Dn = 256;    // feature dim
constexpr float EPS = 1e-4f;

typedef __attribute__((ext_vector_type(8))) short bf16x8;
typedef __attribute__((ext_vector_type(4))) float f32x4;

// f32 -> bf16 round-to-nearest-even
static __device__ __forceinline__ unsigned short f2bf(float x) {
    union { float f; unsigned u; } v; v.f = x;
    return (unsigned short)((v.u + 0x7fffu + ((v.u >> 16) & 1u)) >> 16);
}
static __device__ __forceinline__ float bf2f(unsigned short h) {
    union { unsigned u; float f; } v; v.u = ((unsigned)h) << 16; return v.f;
}
static __device__ __forceinline__ bf16x8 cvt8(const float4 lo, const float4 hi) {
    bf16x8 r;
    r[0] = (short)f2bf(lo.x); r[1] = (short)f2bf(lo.y);
    r[2] = (short)f2bf(lo.z); r[3] = (short)f2bf(lo.w);
    r[4] = (short)f2bf(hi.x); r[5] = (short)f2bf(hi.y);
    r[6] = (short)f2bf(hi.z); r[7] = (short)f2bf(hi.w);
    return r;
}

// ---------------------------------------------------------------------------
// K1: Wb = bf16(G @ F), G = [z ; mu_clamped]  (rows 0..1023 = z, 1024.. = mu)
// 64 rows x 32 cols per block; MFMA with in-register f32->bf16 conversion.
// A-frags: per-lane row loads (2x float4). B-frags: F[k][n] per-j dword loads
// (coalesced across the 16 fragment lanes). No LDS.
// col0==0 blocks also write epsn = EPS*||row||^2; block 256 computes lse.
__global__ __launch_bounds__(256) void w_kernel(const float* __restrict__ z,
                                                const float* __restrict__ mu,
                                                const float* __restrict__ logits,
                                                const float* __restrict__ F,
                                                unsigned short* __restrict__ Wb,  // [2048][256]
                                                float* __restrict__ epsn,         // [2048]
                                                float* __restrict__ lse_p) {
    const int bid = blockIdx.x, tid = threadIdx.x;

    if (bid == 256) {   // lse = logsumexp(logits)
        __shared__ float rl[256];
        float mx = -INFINITY;
        for (int i = tid; i < Cn; i += 256) mx = fmaxf(mx, logits[i]);
        rl[tid] = mx; __syncthreads();
        for (int s = 128; s > 0; s >>= 1) {
            if (tid < s) rl[tid] = fmaxf(rl[tid], rl[tid + s]);
            __syncthreads();
        }
        mx = rl[0]; __syncthreads();
        float sm = 0.f;
        for (int i = tid; i < Cn; i += 256) sm += expf(logits[i] - mx);
        rl[tid] = sm; __syncthreads();
        for (int s = 128; s > 0; s >>= 1) {
            if (tid < s) rl[tid] += rl[tid + s];
            __syncthreads();
        }
        if (tid == 0) *lse_p = mx + logf(rl[0]);
        return;
    }

    const int row0 = (bid >> 3) * 64;   // 32 row tiles over G's 2048 rows
    const int col0 = (bid & 7) * 32;    // 8 col tiles
    const int lane = tid & 63, w = tid >> 6;
    const int wr = (w >> 1) * 32, wc = (w & 1) * 16;
    const int la = lane & 15, kg = lane >> 4;

    // per-lane A row pointers (f32 source)
    const int g0 = row0 + wr + la;
    const int g1 = g0 + 16;
    const float* arow0 = (g0 < 1024) ? &z[(size_t)g0 * Dn]
                                     : &mu[(size_t)min(g0 - 1024, Cn - 1) * Dn];
    const float* arow1 = (g1 < 1024) ? &z[(size_t)g1 * Dn]
                                     : &mu[(size_t)min(g1 - 1024, Cn - 1) * Dn];
    const int bcol = col0 + wc + la;

    f32x4 acc0 = {0.f, 0.f, 0.f, 0.f};
    f32x4 acc1 = {0.f, 0.f, 0.f, 0.f};

#pragma unroll
    for (int kt = 0; kt < 8; ++kt) {
        const int k0 = kt * 32 + kg * 8;
        const float4 a0lo = *(const float4*)&arow0[k0];
        const float4 a0hi = *(const float4*)&arow0[k0 + 4];
        const float4 a1lo = *(const float4*)&arow1[k0];
        const float4 a1hi = *(const float4*)&arow1[k0 + 4];
        bf16x8 b0;
#pragma unroll
        for (int j = 0; j < 8; ++j)
            b0[j] = (short)f2bf(F[(size_t)(k0 + j) * Dn + bcol]);
        const bf16x8 a0 = cvt8(a0lo, a0hi);
        const bf16x8 a1 = cvt8(a1lo, a1hi);
        acc0 = __builtin_amdgcn_mfma_f32_16x16x32_bf16(a0, b0, acc0, 0, 0, 0);
        acc1 = __builtin_amdgcn_mfma_f32_16x16x32_bf16(a1, b0, acc1, 0, 0, 0);
    }

    // C/D: col = lane&15, row = kg*4 + j
    const int rb0 = row0 + wr + kg * 4;
#pragma unroll
    for (int j = 0; j < 4; ++j) {
        Wb[(size_t)(rb0 + j) * Dn + bcol]      = f2bf(acc0[j]);
        Wb[(size_t)(rb0 + 16 + j) * Dn + bcol] = f2bf(acc1[j]);
    }

    if (col0 == 0) {   // epsn = EPS * ||G_row||^2 from f32 inputs
        __shared__ float red[64][4];
        const int r = tid >> 2, q = tid & 3;
        const int g = row0 + r;
        const float* src = (g < 1024) ? &z[(size_t)g * Dn]
                                      : &mu[(size_t)min(g - 1024, Cn - 1) * Dn];
        const float4* p4 = (const float4*)&src[q << 6];
        float s = 0.f;
#pragma unroll
        for (int i = 0; i < 16; ++i) {
            const float4 v = p4[i];
            s += v.x * v.x + v.y * v.y + v.z * v.z + v.w * v.w;
        }
        red[r][q] = s;
        __syncthreads();
        if (tid < 64)
            epsn[row0 + tid] = EPS * (red[tid][0] + red[tid][1] +
                                      red[tid][2] + red[tid][3]);
    }
}

// ---------------------------------------------------------------------------
// K2: out[b][c] = W_Y(b).W_U(c) + rowbias[b] + colbias[c]   (MFMA 64x64 tiles)
// rowbias = -0.5*(||Y_b||^2 + epsn_z), colbias = logit - lse - 0.5*(||U_c||^2 + epsn_mu)
// Norms recomputed in-block from bf16 Wb (L2-resident).
__global__ __launch_bounds__(256) void main_kernel(const unsigned short* __restrict__ Wb,
                                                   const float* __restrict__ epsn,
                                                   const float* __restrict__ logits,
                                                   const float* __restrict__ lse_p,
                                                   float* __restrict__ out) {
    __shared__ float red[64][4];
    __shared__ float rowbias[64], colbias[64];
    const int bid = blockIdx.x, tid = threadIdx.x;
    const int row0 = (bid >> 4) * 64;     // B rows
    const int col0 = (bid & 15) * 64;     // C cols
    const int r = tid >> 2, q = tid & 3;

    {   // Y row norms
        const bf16x8* py = (const bf16x8*)&Wb[(size_t)(row0 + r) * Dn + (q << 6)];
        float s = 0.f;
#pragma unroll
        for (int i = 0; i < 8; ++i) {
            const bf16x8 h = py[i];
#pragma unroll
            for (int j = 0; j < 8; ++j) {
                const float f = bf2f((unsigned short)h[j]);
                s = fmaf(f, f, s);
            }
        }
        red[r][q] = s;
    }
    __syncthreads();
    if (tid < 64)
        rowbias[tid] = -0.5f * (red[tid][0] + red[tid][1] + red[tid][2] +
                                red[tid][3] + epsn[row0 + tid]);
    __syncthreads();
    {   // U row norms
        const bf16x8* pu = (const bf16x8*)&Wb[(size_t)(1024 + col0 + r) * Dn + (q << 6)];
        float s = 0.f;
#pragma unroll
        for (int i = 0; i < 8; ++i) {
            const bf16x8 h = pu[i];
#pragma unroll
            for (int j = 0; j < 8; ++j) {
                const float f = bf2f((unsigned short)h[j]);
                s = fmaf(f, f, s);
            }
        }
        red[r][q] = s;
    }
    __syncthreads();
    if (tid < 64) {
        const int c = col0 + tid;
        colbias[tid] = (c < Cn)
            ? logits[c] - *lse_p - 0.5f * (red[tid][0] + red[tid][1] + red[tid][2] +
                                           red[tid][3] + epsn[1024 + c])
            : 0.f;
    }
    __syncthreads();

    const int lane = tid & 63, w = tid >> 6;
    const int wr = (w >> 1) * 32, wc = (w & 1) * 32;
    const int la = lane & 15, kg = lane >> 4;

    const bf16x8* pa = (const bf16x8*)&Wb[(size_t)(row0 + wr + la) * Dn + kg * 8];
    const bf16x8* pb = (const bf16x8*)&Wb[(size_t)(1024 + col0 + wc + la) * Dn + kg * 8];

    f32x4 acc00 = {0.f, 0.f, 0.f, 0.f};
    f32x4 acc01 = {0.f, 0.f, 0.f, 0.f};
    f32x4 acc10 = {0.f, 0.f, 0.f, 0.f};
    f32x4 acc11 = {0.f, 0.f, 0.f, 0.f};

#pragma unroll
    for (int kt = 0; kt < 8; ++kt) {
        const bf16x8 a0 = pa[kt * 4];
        const bf16x8 a1 = pa[kt * 4 + 512];
        const bf16x8 b0 = pb[kt * 4];
        const bf16x8 b1 = pb[kt * 4 + 512];
        acc00 = __builtin_amdgcn_mfma_f32_16x16x32_bf16(a0, b0, acc00, 0, 0, 0);
        acc01 = __builtin_amdgcn_mfma_f32_16x16x32_bf16(a0, b1, acc01, 0, 0, 0);
        acc10 = __builtin_amdgcn_mfma_f32_16x16x32_bf16(a1, b0, acc10, 0, 0, 0);
        acc11 = __builtin_amdgcn_mfma_f32_16x16x32_bf16(a1, b1, acc11, 0, 0, 0);
    }

    const int rbase = kg * 4;
#define EPI(ACC, RF, CF)                                                        \
    do {                                                                        \
        const int gcl = wc + (CF)*16 + la;                                      \
        const int gc  = col0 + gcl;                                             \
        if (gc < Cn) {                                                          \
            const float cb = colbias[gcl];                                      \
            _Pragma("unroll")                                                   \
            for (int j = 0; j < 4; ++j) {                                       \
                const int rlc = wr + (RF)*16 + rbase + j;                       \
                out[(size_t)(row0 + rlc) * Cn + gc] = ACC[j] + rowbias[rlc] + cb; \
            }                                                                   \
        }                                                                       \
    } while (0)

    EPI(acc00, 0, 0); EPI(acc01, 0, 1); EPI(acc10, 1, 0); EPI(acc11, 1, 1);
#undef EPI
}

// ---------------------------------------------------------------------------
extern "C" void kernel_launch(void* const* d_in, const int* in_sizes, int n_in,
                              void* d_out, int out_size, void* d_ws, size_t ws_size,
                              hipStream_t stream) {
    const float* z      = (const float*)d_in[0];   // [1024][256]
    const float* mu     = (const float*)d_in[1];   // [1000][256]
    const float* logits = (const float*)d_in[2];   // [1000]
    const float* F      = (const float*)d_in[3];   // [256][256]
    float* out = (float*)d_out;                    // [1024][1000]

    char* ws = (char*)d_ws;
    unsigned short* Wb = (unsigned short*)(ws);            // 1 MB [2048][256] bf16
    float* epsn = (float*)(ws + (1 << 20));                // 8 KB [2048]
    float* lse  = epsn + 2048;                             // 4 B

    w_kernel<<<dim3(257), dim3(256), 0, stream>>>(z, mu, logits, F, Wb, epsn, lse);
    main_kernel<<<dim3(256), dim3(256), 0, stream>>>(Wb, epsn, logits, lse, out);
}